// Round 10
// baseline (41.891 us; speedup 1.0000x reference)
//
#include <hip/hip_runtime.h>
#include <math.h>

#define NEG_SLOPE 0.2f
#define LOG2E 1.44269504088896f

#if __has_builtin(__builtin_amdgcn_exp2f)
#define EXP2F __builtin_amdgcn_exp2f
#else
#define EXP2F exp2f
#endif

typedef _Float16 f16x8 __attribute__((ext_vector_type(8)));
typedef __fp16 h16x2 __attribute__((ext_vector_type(2)));   // cvt_pkrtz native type
typedef float f32x4 __attribute__((ext_vector_type(4)));
typedef float f32x2 __attribute__((ext_vector_type(2)));

union PK8 { uint4 u4; _Float16 h[8]; f16x8 v; h16x2 p[4]; };
union PKH { h16x2 v; unsigned int u; unsigned short s[2]; };
union PK1 { unsigned short u; _Float16 h; };

#define WN_CHUNKS (256 * 256 / 8)        // 8192 W-chunks of 8

// ---------------------------------------------------------------------------
// Kernel 0: one-shot f32 -> f16 convert of W only (131 KB). 32 blocks.
// ---------------------------------------------------------------------------
__global__ __launch_bounds__(256) void cvt_w(const float* __restrict__ W,
                                             unsigned short* __restrict__ wf) {
    int idx = blockIdx.x * 256 + threadIdx.x;
    if (idx >= WN_CHUNKS) return;
    const float* src = W + (size_t)idx * 8;
    float4 v0 = *(const float4*)(src);
    float4 v1 = *(const float4*)(src + 4);
    PK8 p;
    p.p[0] = __builtin_amdgcn_cvt_pkrtz(v0.x, v0.y);
    p.p[1] = __builtin_amdgcn_cvt_pkrtz(v0.z, v0.w);
    p.p[2] = __builtin_amdgcn_cvt_pkrtz(v1.x, v1.y);
    p.p[3] = __builtin_amdgcn_cvt_pkrtz(v1.z, v1.w);
    *(uint4*)(wf + (size_t)idx * 8) = p.u4;
}

// ---------------------------------------------------------------------------
// Kernel A: Wx = x @ W.T via f16 MFMA. x consumed f32 directly (packed cvt
// during staging); W from f16 wf. Output f16 [bh][d][j] -> wxtg.
// Grid 512: m0=(bid&255)*64, n0=(bid>>8)*128 -> the two blocks sharing an
// x m-tile are 256 apart => same XCD => 2nd x read is L2-hot.
// ---------------------------------------------------------------------------
__global__ __launch_bounds__(256) void gemm_wxt(const float* __restrict__ x,
                                                const unsigned short* __restrict__ wf,
                                                unsigned short* __restrict__ wxtg) {
    __shared__ __align__(16) unsigned short xs[64 * 64];    // [i][k] f16, row 128B
    __shared__ __align__(16) unsigned short pool[128 * 64]; // ws / tb alias, 16KB
    unsigned short* ws = pool;   // [n][k] f16, row 128B, swz (n&7)<<4
    unsigned short* tb = pool;   // [n][j] f16, row 128B, swz (n&7)<<4 (after GEMM)

    const int tid = threadIdx.x;
    const int bid = blockIdx.x;
    const int m0 = (bid & 255) * 64;
    const int n0 = (bid >> 8) * 128;
    const int w = tid >> 6, l = tid & 63;
    const int q = l >> 4, ln = l & 15;
    const int iw = (w & 1) * 32, nw = (w >> 1) * 64;

    f32x4 acc[2][4];
    #pragma unroll
    for (int g = 0; g < 2; ++g)
        #pragma unroll
        for (int t = 0; t < 4; ++t) acc[g][t] = (f32x4){0.f, 0.f, 0.f, 0.f};

    for (int kc = 0; kc < 256; kc += 64) {
        __syncthreads();
        // stage x tile 64x64 f32 -> f16 (16 elems/thread, packed cvt)
        {
            const int i = tid >> 2, kq = tid & 3;
            const float* src = x + (size_t)(m0 + i) * 256 + kc + kq * 16;
            float4 v0 = *(const float4*)(src + 0);
            float4 v1 = *(const float4*)(src + 4);
            float4 v2 = *(const float4*)(src + 8);
            float4 v3 = *(const float4*)(src + 12);
            PK8 p0, p1;
            p0.p[0] = __builtin_amdgcn_cvt_pkrtz(v0.x, v0.y);
            p0.p[1] = __builtin_amdgcn_cvt_pkrtz(v0.z, v0.w);
            p0.p[2] = __builtin_amdgcn_cvt_pkrtz(v1.x, v1.y);
            p0.p[3] = __builtin_amdgcn_cvt_pkrtz(v1.z, v1.w);
            p1.p[0] = __builtin_amdgcn_cvt_pkrtz(v2.x, v2.y);
            p1.p[1] = __builtin_amdgcn_cvt_pkrtz(v2.z, v2.w);
            p1.p[2] = __builtin_amdgcn_cvt_pkrtz(v3.x, v3.y);
            p1.p[3] = __builtin_amdgcn_cvt_pkrtz(v3.z, v3.w);
            int b0 = i * 128 + kq * 32;
            *(uint4*)((char*)xs + (b0 ^ ((i & 7) << 4))) = p0.u4;
            *(uint4*)((char*)xs + ((b0 + 16) ^ ((i & 7) << 4))) = p1.u4;
        }
        // stage W tile 128x64 u16: 1024 uint4, 4/thread
        #pragma unroll
        for (int p = 0; p < 4; ++p) {
            int idx = p * 256 + tid;
            int n = idx >> 3, c = idx & 7;
            uint4 v = *(const uint4*)(wf + (size_t)(n0 + n) * 256 + kc + c * 8);
            *(uint4*)((char*)ws + ((n * 128 + c * 16) ^ ((n & 7) << 4))) = v;
        }
        __syncthreads();

        #pragma unroll
        for (int ks = 0; ks < 2; ++ks) {
            const int kb = ks * 64 + q * 16;
            f16x8 af[2];
            #pragma unroll
            for (int g = 0; g < 2; ++g) {
                int row = iw + g * 16 + ln;
                uint4 raw = *(const uint4*)((const char*)xs +
                            ((row * 128 + kb) ^ ((row & 7) << 4)));
                PK8 pk; pk.u4 = raw;
                af[g] = pk.v;
            }
            #pragma unroll
            for (int t = 0; t < 4; ++t) {
                int n = nw + t * 16 + ln;
                uint4 raw = *(const uint4*)((const char*)ws +
                            ((n * 128 + kb) ^ ((n & 7) << 4)));
                PK8 pk; pk.u4 = raw;
                f16x8 bf = pk.v;
                acc[0][t] = __builtin_amdgcn_mfma_f32_16x16x32_f16(af[0], bf, acc[0][t], 0, 0, 0);
                acc[1][t] = __builtin_amdgcn_mfma_f32_16x16x32_f16(af[1], bf, acc[1][t], 0, 0, 0);
            }
        }
    }

    __syncthreads();   // done reading ws -> tb may overwrite
    // C frags -> transpose buffer tb[n][j_local] f16
    #pragma unroll
    for (int g = 0; g < 2; ++g)
        #pragma unroll
        for (int t = 0; t < 4; ++t)
            #pragma unroll
            for (int r = 0; r < 4; ++r) {
                int n  = nw + t * 16 + ln;            // C col
                int jl = iw + g * 16 + q * 4 + r;     // C row
                PK1 hv; hv.h = (_Float16)acc[g][t][r];
                *(unsigned short*)((char*)tb + ((n * 128 + jl * 2) ^ ((n & 7) << 4))) = hv.u;
            }
    __syncthreads();
    // coalesced readout: 1024 16B chunks, 4/thread
    {
        const int b = m0 >> 9, j0 = m0 & 511;
        #pragma unroll
        for (int p = 0; p < 4; ++p) {
            int idx = p * 256 + tid;
            int n = idx >> 3, c = idx & 7;
            uint4 v = *(const uint4*)((const char*)tb + ((n * 128 + c * 16) ^ ((n & 7) << 4)));
            int nn = n0 + n;                          // = h*32 + d
            *(uint4*)(wxtg + ((size_t)(b * 256 + nn) * 512 + j0 + c * 8)) = v;
        }
    }
}

// ---------------------------------------------------------------------------
// Kernel B: scores + softmax + PV + ELU. Grid 512 = (half, b, h).
// 512 thr = 8 waves; wave owns 32 i-rows. P-gen in packed-f32 (v_pk_*) +
// cvt_pkrtz packing; kk-loop unrolled x2 for ILP.
// ---------------------------------------------------------------------------
__global__ __launch_bounds__(512, 4) void gat_attn(const unsigned short* __restrict__ wxtg,
                                                   const float* __restrict__ attn,
                                                   float* __restrict__ out) {
    __shared__ __align__(16) unsigned short wxt[32 * 512];  // [d][j] f16, row 1KB, swz (d&7)<<4
    __shared__ float stf[512];    // s_tgt * LOG2E
    __shared__ float ssrc[512];   // s_src * LOG2E
    __shared__ float red_s[8];

    const int bid = blockIdx.x;
    const int bh = bid & 255, half = bid >> 8;
    const int b = bh >> 3, h = bh & 7;
    const int tid = threadIdx.x;
    const int w = tid >> 6, l = tid & 63;
    const int q = l >> 4, ln = l & 15;

    // ---- stage WxT slice: 32KB straight f16 copy ----
    {
        const unsigned short* src = wxtg + (size_t)bh * 32 * 512;
        const int d = tid >> 4, cs = tid & 15;
        #pragma unroll
        for (int p = 0; p < 4; ++p) {
            int c = p * 16 + cs;
            uint4 v = *(const uint4*)(src + d * 512 + c * 8);
            *(uint4*)((char*)wxt + ((d * 1024 + c * 16) ^ ((d & 7) << 4))) = v;
        }
    }
    __syncthreads();

    // ---- scores from LDS tile: thread j = tid ----
    {
        const int j = tid;
        float ss = 0.f, st = 0.f;
        #pragma unroll
        for (int d = 0; d < 32; ++d) {
            PK1 hv;
            hv.u = *(const unsigned short*)((const char*)wxt +
                    ((d * 1024 + j * 2) ^ ((d & 7) << 4)));
            float v = (float)hv.h;
            ss += v * attn[h * 64 + d];
            st += v * attn[h * 64 + 32 + d];
        }
        ssrc[j] = ss * LOG2E;
        float stv = st * LOG2E;
        stf[j] = stv;
        float m = stv;
        #pragma unroll
        for (int off = 32; off > 0; off >>= 1)
            m = fmaxf(m, __shfl_xor(m, off));
        if (l == 0) red_s[w] = m;
    }
    __syncthreads();
    float maxtK = red_s[0];
    #pragma unroll
    for (int ww = 1; ww < 8; ++ww) maxtK = fmaxf(maxtK, red_s[ww]);

    // ---- wave owns rows i = half*256 + w*32 + g*16 + ln ----
    const int ibase = half * 256 + w * 32;
    float ciK[2], miK[2];
    #pragma unroll
    for (int g = 0; g < 2; ++g) {
        float cc = ssrc[ibase + g * 16 + ln];
        float cm = cc + maxtK;
        miK[g] = fmaxf(cm, NEG_SLOPE * cm);
        ciK[g] = cc;
    }

    f32x4 acc[2][2];
    #pragma unroll
    for (int g = 0; g < 2; ++g) {
        acc[g][0] = (f32x4){0.f, 0.f, 0.f, 0.f};
        acc[g][1] = (f32x4){0.f, 0.f, 0.f, 0.f};
    }
    f32x2 pdv[2] = {(f32x2){0.f, 0.f}, (f32x2){0.f, 0.f}};

    #pragma unroll 2
    for (int kk = 0; kk < 16; ++kk) {
        const int j0 = kk * 32 + q * 8;
        f32x2 stp[4];
        {
            float4 s0 = *(const float4*)(stf + j0);
            float4 s1 = *(const float4*)(stf + j0 + 4);
            stp[0] = (f32x2){s0.x, s0.y};
            stp[1] = (f32x2){s0.z, s0.w};
            stp[2] = (f32x2){s1.x, s1.y};
            stp[3] = (f32x2){s1.z, s1.w};
        }

        f16x8 bf[2];
        #pragma unroll
        for (int dt = 0; dt < 2; ++dt) {
            int d = dt * 16 + ln;
            int bb = d * 1024 + kk * 64 + q * 16;
            uint4 raw = *(const uint4*)((const char*)wxt + (bb ^ ((d & 7) << 4)));
            PK8 pk; pk.u4 = raw;
            bf[dt] = pk.v;
        }

        #pragma unroll
        for (int g = 0; g < 2; ++g) {
            const f32x2 ci2 = (f32x2){ciK[g], ciK[g]};
            const f32x2 mi2 = (f32x2){miK[g], miK[g]};
            PK8 pa;
            #pragma unroll
            for (int pr = 0; pr < 4; ++pr) {
                f32x2 e  = ci2 + stp[pr];                           // v_pk_add
                f32x2 a1 = e - mi2;                                 // v_pk_add(-)
                f32x2 a2 = (f32x2){NEG_SLOPE, NEG_SLOPE} * e - mi2; // v_pk_fma
                float m0 = fmaxf(a1.x, a2.x);
                float m1 = fmaxf(a1.y, a2.y);
                float p0 = EXP2F(m0);
                float p1 = EXP2F(m1);
                pdv[g] += (f32x2){p0, p1};                          // v_pk_add
                pa.p[pr] = __builtin_amdgcn_cvt_pkrtz(p0, p1);      // 1 cvt
            }
            acc[g][0] = __builtin_amdgcn_mfma_f32_16x16x32_f16(pa.v, bf[0], acc[g][0], 0, 0, 0);
            acc[g][1] = __builtin_amdgcn_mfma_f32_16x16x32_f16(pa.v, bf[1], acc[g][1], 0, 0, 0);
        }
    }

    float inv[2];
    #pragma unroll
    for (int g = 0; g < 2; ++g) {
        float s = pdv[g].x + pdv[g].y;
        s += __shfl_xor(s, 16);
        s += __shfl_xor(s, 32);
        inv[g] = 1.f / s;
    }
    #pragma unroll
    for (int g = 0; g < 2; ++g)
        #pragma unroll
        for (int dt = 0; dt < 2; ++dt)
            #pragma unroll
            for (int r = 0; r < 4; ++r) {
                int row = q * 4 + r;
                float dn = __shfl(inv[g], row);    // lane 'row' holds denom for i-local=row
                float o = acc[g][dt][r] * dn;
                o = o > 0.f ? o : (__expf(o) - 1.f);
                size_t i = (size_t)(b * 512 + ibase + g * 16 + row);
                out[i * 256 + h * 32 + dt * 16 + ln] = o;
            }
}

// ---------------------------------------------------------------------------
extern "C" void kernel_launch(void* const* d_in, const int* in_sizes, int n_in,
                              void* d_out, int out_size, void* d_ws, size_t ws_size,
                              hipStream_t stream) {
    const float* x    = (const float*)d_in[0];   // (32,512,256)
    const float* W    = (const float*)d_in[1];   // (256,256)
    const float* attn = (const float*)d_in[2];   // (1,8,64)
    float* out = (float*)d_out;                  // (32,512,256)

    unsigned short* wf   = (unsigned short*)d_ws;             // f16 W, 131 KB
    unsigned short* wxtg = wf + 256 * 256;                    // f16 [bh][d][j], 8.39 MB

    cvt_w<<<WN_CHUNKS / 256, 256, 0, stream>>>(W, wf);
    gemm_wxt<<<512, 256, 0, stream>>>(x, wf, wxtg);
    gat_attn<<<512, 512, 0, stream>>>(wxtg, attn, out);
}

// Round 11
// 41.298 us; speedup vs baseline: 1.0144x; 1.0144x over previous
//
#include <hip/hip_runtime.h>
#include <math.h>

#define NEG_SLOPE 0.2f
#define LOG2E 1.44269504088896f

#if __has_builtin(__builtin_amdgcn_exp2f)
#define EXP2F __builtin_amdgcn_exp2f
#else
#define EXP2F exp2f
#endif

typedef _Float16 f16x8 __attribute__((ext_vector_type(8)));
typedef __fp16 h16x2 __attribute__((ext_vector_type(2)));   // cvt_pkrtz native type
typedef float f32x4 __attribute__((ext_vector_type(4)));
typedef float f32x2 __attribute__((ext_vector_type(2)));

union PK8 { uint4 u4; _Float16 h[8]; f16x8 v; h16x2 p[4]; };
union PK1 { unsigned short u; _Float16 h; };

#define WN_CHUNKS (256 * 256 / 8)        // 8192 W-chunks of 8

// ---------------------------------------------------------------------------
// Kernel 0: one-shot f32 -> f16 convert of W (131 KB). 32 blocks.
// ---------------------------------------------------------------------------
__global__ __launch_bounds__(256) void cvt_w(const float* __restrict__ W,
                                             unsigned short* __restrict__ wf) {
    int idx = blockIdx.x * 256 + threadIdx.x;
    if (idx >= WN_CHUNKS) return;
    const float* src = W + (size_t)idx * 8;
    float4 v0 = *(const float4*)(src);
    float4 v1 = *(const float4*)(src + 4);
    PK8 p;
    p.p[0] = __builtin_amdgcn_cvt_pkrtz(v0.x, v0.y);
    p.p[1] = __builtin_amdgcn_cvt_pkrtz(v0.z, v0.w);
    p.p[2] = __builtin_amdgcn_cvt_pkrtz(v1.x, v1.y);
    p.p[3] = __builtin_amdgcn_cvt_pkrtz(v1.z, v1.w);
    *(uint4*)(wf + (size_t)idx * 8) = p.u4;
}

// ---------------------------------------------------------------------------
// Kernel A: Wx = x @ W.T via f16 MFMA. Output f16 [bh][d][j] -> wxtg.
// Grid 1024: m0=(bid&255)*64 (64 i-rows), n0=(bid>>8)*64 (64 n-cols).
// LDS 16KB -> 4 blocks/CU = 16 waves/CU (was 8). Blocks sharing an x m-tile
// are 256 apart => same XCD => re-reads L2-hot. W slice (8KB/n-tile) L2-hot.
// ---------------------------------------------------------------------------
__global__ __launch_bounds__(256) void gemm_wxt(const float* __restrict__ x,
                                                const unsigned short* __restrict__ wf,
                                                unsigned short* __restrict__ wxtg) {
    __shared__ __align__(16) unsigned short xs[64 * 64];    // [i][k] f16, row 128B
    __shared__ __align__(16) unsigned short pool[64 * 64];  // ws / tb alias, 8KB
    unsigned short* ws = pool;   // [n][k] f16, row 128B, swz (n&7)<<4
    unsigned short* tb = pool;   // [n][j] f16, row 128B, swz (n&7)<<4 (after GEMM)

    const int tid = threadIdx.x;
    const int bid = blockIdx.x;
    const int m0 = (bid & 255) * 64;
    const int n0 = (bid >> 8) * 64;
    const int w = tid >> 6, l = tid & 63;
    const int q = l >> 4, ln = l & 15;
    const int iw = (w & 1) * 32, nw = (w >> 1) * 32;

    f32x4 acc[2][2];
    #pragma unroll
    for (int g = 0; g < 2; ++g)
        #pragma unroll
        for (int t = 0; t < 2; ++t) acc[g][t] = (f32x4){0.f, 0.f, 0.f, 0.f};

    for (int kc = 0; kc < 256; kc += 64) {
        __syncthreads();
        // stage x tile 64x64 f32 -> f16 (16 elems/thread, packed cvt)
        {
            const int i = tid >> 2, kq = tid & 3;
            const float* src = x + (size_t)(m0 + i) * 256 + kc + kq * 16;
            float4 v0 = *(const float4*)(src + 0);
            float4 v1 = *(const float4*)(src + 4);
            float4 v2 = *(const float4*)(src + 8);
            float4 v3 = *(const float4*)(src + 12);
            PK8 p0, p1;
            p0.p[0] = __builtin_amdgcn_cvt_pkrtz(v0.x, v0.y);
            p0.p[1] = __builtin_amdgcn_cvt_pkrtz(v0.z, v0.w);
            p0.p[2] = __builtin_amdgcn_cvt_pkrtz(v1.x, v1.y);
            p0.p[3] = __builtin_amdgcn_cvt_pkrtz(v1.z, v1.w);
            p1.p[0] = __builtin_amdgcn_cvt_pkrtz(v2.x, v2.y);
            p1.p[1] = __builtin_amdgcn_cvt_pkrtz(v2.z, v2.w);
            p1.p[2] = __builtin_amdgcn_cvt_pkrtz(v3.x, v3.y);
            p1.p[3] = __builtin_amdgcn_cvt_pkrtz(v3.z, v3.w);
            int b0 = i * 128 + kq * 32;
            *(uint4*)((char*)xs + (b0 ^ ((i & 7) << 4))) = p0.u4;
            *(uint4*)((char*)xs + ((b0 + 16) ^ ((i & 7) << 4))) = p1.u4;
        }
        // stage W tile 64x64 u16: 512 uint4, 2/thread
        #pragma unroll
        for (int p = 0; p < 2; ++p) {
            int idx = p * 256 + tid;
            int n = idx >> 3, c = idx & 7;
            uint4 v = *(const uint4*)(wf + (size_t)(n0 + n) * 256 + kc + c * 8);
            *(uint4*)((char*)ws + ((n * 128 + c * 16) ^ ((n & 7) << 4))) = v;
        }
        __syncthreads();

        #pragma unroll
        for (int ks = 0; ks < 2; ++ks) {
            const int kb = ks * 64 + q * 16;
            f16x8 af[2];
            #pragma unroll
            for (int g = 0; g < 2; ++g) {
                int row = iw + g * 16 + ln;
                uint4 raw = *(const uint4*)((const char*)xs +
                            ((row * 128 + kb) ^ ((row & 7) << 4)));
                PK8 pk; pk.u4 = raw;
                af[g] = pk.v;
            }
            #pragma unroll
            for (int t = 0; t < 2; ++t) {
                int n = nw + t * 16 + ln;
                uint4 raw = *(const uint4*)((const char*)ws +
                            ((n * 128 + kb) ^ ((n & 7) << 4)));
                PK8 pk; pk.u4 = raw;
                f16x8 bf = pk.v;
                acc[0][t] = __builtin_amdgcn_mfma_f32_16x16x32_f16(af[0], bf, acc[0][t], 0, 0, 0);
                acc[1][t] = __builtin_amdgcn_mfma_f32_16x16x32_f16(af[1], bf, acc[1][t], 0, 0, 0);
            }
        }
    }

    __syncthreads();   // done reading ws -> tb may overwrite
    // C frags -> transpose buffer tb[n][j_local] f16
    #pragma unroll
    for (int g = 0; g < 2; ++g)
        #pragma unroll
        for (int t = 0; t < 2; ++t)
            #pragma unroll
            for (int r = 0; r < 4; ++r) {
                int n  = nw + t * 16 + ln;            // C col
                int jl = iw + g * 16 + q * 4 + r;     // C row
                PK1 hv; hv.h = (_Float16)acc[g][t][r];
                *(unsigned short*)((char*)tb + ((n * 128 + jl * 2) ^ ((n & 7) << 4))) = hv.u;
            }
    __syncthreads();
    // coalesced readout: 512 16B chunks, 2/thread
    {
        const int b = m0 >> 9, j0 = m0 & 511;
        #pragma unroll
        for (int p = 0; p < 2; ++p) {
            int idx = p * 256 + tid;
            int n = idx >> 3, c = idx & 7;
            uint4 v = *(const uint4*)((const char*)tb + ((n * 128 + c * 16) ^ ((n & 7) << 4)));
            int nn = n0 + n;                          // = h*32 + d
            *(uint4*)(wxtg + ((size_t)(b * 256 + nn) * 512 + j0 + c * 8)) = v;
        }
    }
}

// ---------------------------------------------------------------------------
// Kernel B: scores + softmax + PV + ELU. Grid 1024 = (quarter, b, h).
// 512 thr = 8 waves; wave owns 16 i-rows. launch_bounds(512,8) + LDS 36KB
// -> 4 blocks/CU = 8 waves/SIMD (max occupancy; was 4). Work per output
// unchanged; quarters of a bh share an XCD (256 % 8 == 0) so the wxtg
// slice is L2-hot for quarters 1-3.
// ---------------------------------------------------------------------------
__global__ __launch_bounds__(512, 8) void gat_attn(const unsigned short* __restrict__ wxtg,
                                                   const float* __restrict__ attn,
                                                   float* __restrict__ out) {
    __shared__ __align__(16) unsigned short wxt[32 * 512];  // [d][j] f16, row 1KB, swz (d&7)<<4
    __shared__ float stf[512];    // s_tgt * LOG2E
    __shared__ float ssrc[512];   // s_src * LOG2E
    __shared__ float red_s[8];

    const int bid = blockIdx.x;
    const int bh = bid & 255, quart = bid >> 8;
    const int b = bh >> 3, h = bh & 7;
    const int tid = threadIdx.x;
    const int w = tid >> 6, l = tid & 63;
    const int q = l >> 4, ln = l & 15;

    // ---- stage WxT slice: 32KB straight f16 copy ----
    {
        const unsigned short* src = wxtg + (size_t)bh * 32 * 512;
        const int d = tid >> 4, cs = tid & 15;
        #pragma unroll
        for (int p = 0; p < 4; ++p) {
            int c = p * 16 + cs;
            uint4 v = *(const uint4*)(src + d * 512 + c * 8);
            *(uint4*)((char*)wxt + ((d * 1024 + c * 16) ^ ((d & 7) << 4))) = v;
        }
    }
    __syncthreads();

    // ---- scores from LDS tile: thread j = tid ----
    {
        const int j = tid;
        float ss = 0.f, st = 0.f;
        #pragma unroll
        for (int d = 0; d < 32; ++d) {
            PK1 hv;
            hv.u = *(const unsigned short*)((const char*)wxt +
                    ((d * 1024 + j * 2) ^ ((d & 7) << 4)));
            float v = (float)hv.h;
            ss += v * attn[h * 64 + d];
            st += v * attn[h * 64 + 32 + d];
        }
        ssrc[j] = ss * LOG2E;
        float stv = st * LOG2E;
        stf[j] = stv;
        float m = stv;
        #pragma unroll
        for (int off = 32; off > 0; off >>= 1)
            m = fmaxf(m, __shfl_xor(m, off));
        if (l == 0) red_s[w] = m;
    }
    __syncthreads();
    float maxtK = red_s[0];
    #pragma unroll
    for (int ww = 1; ww < 8; ++ww) maxtK = fmaxf(maxtK, red_s[ww]);

    // ---- wave owns 16 rows: i = quart*128 + w*16 + ln ----
    const int ibase = quart * 128 + w * 16;
    float ciK, miK;
    {
        float cc = ssrc[ibase + ln];
        float cm = cc + maxtK;
        miK = fmaxf(cm, NEG_SLOPE * cm);
        ciK = cc;
    }

    f32x4 acc0 = (f32x4){0.f, 0.f, 0.f, 0.f};
    f32x4 acc1 = (f32x4){0.f, 0.f, 0.f, 0.f};
    f32x2 pdv = (f32x2){0.f, 0.f};

    for (int kk = 0; kk < 16; ++kk) {
        const int j0 = kk * 32 + q * 8;
        f32x2 stp[4];
        {
            float4 s0 = *(const float4*)(stf + j0);
            float4 s1 = *(const float4*)(stf + j0 + 4);
            stp[0] = (f32x2){s0.x, s0.y};
            stp[1] = (f32x2){s0.z, s0.w};
            stp[2] = (f32x2){s1.x, s1.y};
            stp[3] = (f32x2){s1.z, s1.w};
        }

        f16x8 bf[2];
        #pragma unroll
        for (int dt = 0; dt < 2; ++dt) {
            int d = dt * 16 + ln;
            int bb = d * 1024 + kk * 64 + q * 16;
            uint4 raw = *(const uint4*)((const char*)wxt + (bb ^ ((d & 7) << 4)));
            PK8 pk; pk.u4 = raw;
            bf[dt] = pk.v;
        }

        const f32x2 ci2 = (f32x2){ciK, ciK};
        const f32x2 mi2 = (f32x2){miK, miK};
        PK8 pa;
        #pragma unroll
        for (int pr = 0; pr < 4; ++pr) {
            f32x2 e  = ci2 + stp[pr];                           // v_pk_add
            f32x2 a1 = e - mi2;                                 // v_pk_add(-)
            f32x2 a2 = (f32x2){NEG_SLOPE, NEG_SLOPE} * e - mi2; // v_pk_fma
            float m0 = fmaxf(a1.x, a2.x);
            float m1 = fmaxf(a1.y, a2.y);
            float p0 = EXP2F(m0);
            float p1 = EXP2F(m1);
            pdv += (f32x2){p0, p1};                             // v_pk_add
            pa.p[pr] = __builtin_amdgcn_cvt_pkrtz(p0, p1);      // 1 cvt
        }
        acc0 = __builtin_amdgcn_mfma_f32_16x16x32_f16(pa.v, bf[0], acc0, 0, 0, 0);
        acc1 = __builtin_amdgcn_mfma_f32_16x16x32_f16(pa.v, bf[1], acc1, 0, 0, 0);
    }

    float inv;
    {
        float s = pdv.x + pdv.y;
        s += __shfl_xor(s, 16);
        s += __shfl_xor(s, 32);
        inv = 1.f / s;
    }
    #pragma unroll
    for (int dt = 0; dt < 2; ++dt) {
        f32x4 a = dt ? acc1 : acc0;
        #pragma unroll
        for (int r = 0; r < 4; ++r) {
            int row = q * 4 + r;
            float dn = __shfl(inv, row);    // lane 'row' holds denom for i-local=row
            float o = a[r] * dn;
            o = o > 0.f ? o : (__expf(o) - 1.f);
            size_t i = (size_t)(b * 512 + ibase + row);
            out[i * 256 + h * 32 + dt * 16 + ln] = o;
        }
    }
}

// ---------------------------------------------------------------------------
extern "C" void kernel_launch(void* const* d_in, const int* in_sizes, int n_in,
                              void* d_out, int out_size, void* d_ws, size_t ws_size,
                              hipStream_t stream) {
    const float* x    = (const float*)d_in[0];   // (32,512,256)
    const float* W    = (const float*)d_in[1];   // (256,256)
    const float* attn = (const float*)d_in[2];   // (1,8,64)
    float* out = (float*)d_out;                  // (32,512,256)

    unsigned short* wf   = (unsigned short*)d_ws;             // f16 W, 131 KB
    unsigned short* wxtg = wf + 256 * 256;                    // f16 [bh][d][j], 8.39 MB

    cvt_w<<<WN_CHUNKS / 256, 256, 0, stream>>>(W, wf);
    gemm_wxt<<<1024, 256, 0, stream>>>(x, wf, wxtg);
    gat_attn<<<1024, 512, 0, stream>>>(wxtg, attn, out);
}